// Round 5
// baseline (14191.510 us; speedup 1.0000x reference)
//
#include <hip/hip_runtime.h>
#include <hip/hip_bf16.h>
#include <cstdint>
#include <cstddef>

// ---------------------------------------------------------------------------
// Model dims: NL=32, D=256, DI=512, N=16, R=16, K=4, V=4096, FF=1024, B=32, L=256
// R8: mega-kernel. 96 per-layer dispatch boundaries -> in-kernel grid barriers
//   (two-level counter tree, agent-scope release/acquire, 2ms timeout bail ->
//   fails visibly, never hangs). 6 dispatches total (was 70).
//   Same-block P2/P3 chunk mapping => sXCf/sDBC persist in LDS across the
//   barrier: P3 conv recompute, XZ xm re-read, and DBC global buffer GONE.
//   Phases: P1 in_proj 128x128 tile (8 waves); P2 conv+silu+x_proj+pass1;
//   P3 prefix+scan2+gate+out_proj+resid+LN.  512 blk x 512 thr, (512,4),
//   LDS 69.9KB -> 2 blocks/CU resident (139.8KB < 160KB).
// ---------------------------------------------------------------------------

typedef __bf16 v8bf __attribute__((ext_vector_type(8)));
typedef float  v4f  __attribute__((ext_vector_type(4)));

__device__ __forceinline__ void async_copy16(const void* g, void* l) {
  __builtin_amdgcn_global_load_lds((const __attribute__((address_space(1))) void*)g,
                                   (__attribute__((address_space(3))) void*)l, 16, 0, 0);
}

__device__ __forceinline__ float bf(__bf16 v) { return (float)v; }

// ---------------- workspace layout (bytes) ---------------------------------
constexpr size_t OFF_WIN  = 0;           // bf16 32*1024*256   end 16,777,216
constexpr size_t OFF_WXP  = 16777216;    // bf16 32*48*512     end 18,350,080
constexpr size_t OFF_WOUT = 18350080;    // bf16 32*256*512    end 26,738,688
constexpr size_t OFF_WW1  = 26738688;    // bf16 1024*256      end 27,262,976
constexpr size_t OFF_WW2  = 27262976;    // bf16 4096*1024     end 35,651,584
constexpr size_t OFF_X    = 35651584;    // f32  8192*256      end 44,040,192
constexpr size_t OFF_H    = 44040192;    // bf16 8192*256      end 48,234,496
constexpr size_t OFF_XZ   = 48234496;    // bf16 8192*1024     end 65,011,712
constexpr size_t OFF_PART = 66584576;    // f32  15*32*512*16  end 82,313,216
constexpr size_t OFF_SS   = 82313216;    // f32  15*32*512     end 83,296,256
constexpr size_t OFF_A2   = 83296256;    // f32  32*512*16     end 84,344,832
constexpr size_t OFF_BAR  = 84344832;    // int  544 (34x16 pad) end 84,347,008
// head aliases: XB -> OFF_PART, HH -> OFF_PART+8388608 (end 91.75MB) — BAR/A2/SS
// are dead by head time (recomputed each replay by f2b_multi). <98MB proven.

// ---------------- batched f32 -> bf16 weight conversion + A2 + BAR reset ---
__global__ __launch_bounds__(256)
void f2b_multi(const float* __restrict__ s0, const float* __restrict__ s1,
               const float* __restrict__ s2, const float* __restrict__ s3,
               const float* __restrict__ s4, const float* __restrict__ s5,
               char* __restrict__ ws) {
  if (blockIdx.x == 0) {               // zero grid-barrier state each replay
    int* bar = (int*)(ws + OFF_BAR);
    bar[threadIdx.x] = 0;
    bar[threadIdx.x + 256] = 0;
    if (threadIdx.x < 32) bar[threadIdx.x + 512] = 0;
  }
  size_t i = (size_t)blockIdx.x * 256 + threadIdx.x;
  if (i < 8388608) { ((__bf16*)(ws + OFF_WIN))[i] = (__bf16)s0[i]; return; }
  i -= 8388608;
  if (i < 786432)  { ((__bf16*)(ws + OFF_WXP))[i] = (__bf16)s1[i]; return; }
  i -= 786432;
  if (i < 4194304) { ((__bf16*)(ws + OFF_WOUT))[i] = (__bf16)s2[i]; return; }
  i -= 4194304;
  if (i < 262144)  { ((__bf16*)(ws + OFF_WW1))[i] = (__bf16)s3[i]; return; }
  i -= 262144;
  if (i < 4194304) { ((__bf16*)(ws + OFF_WW2))[i] = (__bf16)s4[i]; return; }
  i -= 4194304;
  ((float*)(ws + OFF_A2))[i] = -1.4426950408889634f * __expf(s5[i]);
}

__global__ __launch_bounds__(256) void f2b_k(const float* __restrict__ X,
                                             __bf16* __restrict__ O) {
  size_t i = (size_t)blockIdx.x * 256 + threadIdx.x;
  O[i] = (__bf16)X[i];
}

// ---------------- embed + layer-0 LN ---------------------------------------
__global__ __launch_bounds__(256)
void embed_ln_k(const int* __restrict__ tok, const float* __restrict__ emb,
                const float* __restrict__ w, const float* __restrict__ b,
                float* __restrict__ X, __bf16* __restrict__ H) {
  int row = blockIdx.x;
  int t   = threadIdx.x;
  float v = emb[(size_t)tok[row] * 256 + t];
  X[(size_t)row * 256 + t] = v;
  float s = v, q = v * v;
  #pragma unroll
  for (int o = 32; o > 0; o >>= 1) { s += __shfl_xor(s, o); q += __shfl_xor(q, o); }
  __shared__ float ss[4], qq[4];
  int wv = t >> 6;
  if ((t & 63) == 0) { ss[wv] = s; qq[wv] = q; }
  __syncthreads();
  s = ss[0] + ss[1] + ss[2] + ss[3];
  q = qq[0] + qq[1] + qq[2] + qq[3];
  float mu  = s * (1.f / 256.f);
  float var = q * (1.f / 256.f) - mu * mu;
  float r   = rsqrtf(var + 1e-5f);
  H[(size_t)row * 256 + t] = (__bf16)((v - mu) * r * w[t] + b[t]);
}

// ---------------- generic MFMA bf16 GEMM (head only) -----------------------
template <int EPI>
__global__ __launch_bounds__(256, 2)
void gemm_bt(const __bf16* __restrict__ A, const __bf16* __restrict__ W,
             void* outp, const float* __restrict__ bias, int M, int N, int K) {
  __shared__ __align__(16) __bf16 sA[128 * 32];
  __shared__ __align__(16) __bf16 sB[128 * 32];
  const int tid  = threadIdx.x;
  const int bm0  = blockIdx.y << 7;
  const int bn0  = blockIdx.x << 7;
  const int lane = tid & 63;
  const int wv   = tid >> 6;
  const int wm   = (wv >> 1) << 6;
  const int wn   = (wv & 1) << 6;
  const int lr   = lane & 15;
  const int lk   = lane >> 4;

  v4f acc[4][4] = {};

  const int r0 = tid >> 2;
  const int c0 = (tid & 3) << 3;
  const int wbase = (tid & ~63) << 3;

  const __bf16* gA0 = A + (size_t)(bm0 + r0) * K + c0;
  const __bf16* gA1 = A + (size_t)(bm0 + 64 + r0) * K + c0;
  const __bf16* gB0 = W + (size_t)(bn0 + r0) * K + c0;
  const __bf16* gB1 = W + (size_t)(bn0 + 64 + r0) * K + c0;

  for (int kk = 0; kk < K; kk += 32) {
    async_copy16(gA0 + kk, sA + wbase);
    async_copy16(gA1 + kk, sA + 2048 + wbase);
    async_copy16(gB0 + kk, sB + wbase);
    async_copy16(gB1 + kk, sB + 2048 + wbase);
    __syncthreads();
    v8bf af[4], bfr[4];
    #pragma unroll
    for (int i = 0; i < 4; ++i)
      af[i] = *(const v8bf*)(sA + ((wm + i * 16 + lr) << 5) + (lk << 3));
    #pragma unroll
    for (int j = 0; j < 4; ++j)
      bfr[j] = *(const v8bf*)(sB + ((wn + j * 16 + lr) << 5) + (lk << 3));
    #pragma unroll
    for (int i = 0; i < 4; ++i)
      #pragma unroll
      for (int j = 0; j < 4; ++j)
        acc[i][j] = __builtin_amdgcn_mfma_f32_16x16x32_bf16(af[i], bfr[j], acc[i][j], 0, 0, 0);
    __syncthreads();
  }

  #pragma unroll
  for (int i = 0; i < 4; ++i) {
    #pragma unroll
    for (int j = 0; j < 4; ++j) {
      int gc = bn0 + wn + j * 16 + lr;
      #pragma unroll
      for (int v = 0; v < 4; ++v) {
        int gr = bm0 + wm + i * 16 + (lk << 2) + v;
        float val = acc[i][j][v];
        size_t idx = (size_t)gr * N + gc;
        if (EPI == 0) {
          ((__bf16*)outp)[idx] = (__bf16)val;
        } else if (EPI == 1) {
          val += bias[gc]; val = fmaxf(val, 0.f);
          ((__bf16*)outp)[idx] = (__bf16)val;
        } else {
          ((float*)outp)[idx] = val + bias[gc];
        }
      }
    }
  }
}

// ---------------- grid barrier (two-level, timeout-bailing) ----------------
// BAR layout (ints): [g*16] g=0..31 group counters; [512] root; [528] phase.
__device__ __forceinline__ void gbar(int* BAR, int ph) {
  __syncthreads();
  if (threadIdx.x == 0) {
    __threadfence();
    int* cg   = BAR + ((blockIdx.x >> 4) << 4);
    int* root = BAR + 512;
    int* phs  = BAR + 528;
    bool last = false;
    int p = __hip_atomic_fetch_add(cg, 1, __ATOMIC_ACQ_REL, __HIP_MEMORY_SCOPE_AGENT);
    if (p == 15) {
      int q = __hip_atomic_fetch_add(root, 1, __ATOMIC_ACQ_REL, __HIP_MEMORY_SCOPE_AGENT);
      last = (q == 31);
    }
    if (last) {
      #pragma unroll 1
      for (int i = 0; i <= 32; ++i)
        __hip_atomic_store(BAR + i * 16, 0, __ATOMIC_RELAXED, __HIP_MEMORY_SCOPE_AGENT);
      __hip_atomic_store(phs, ph, __ATOMIC_RELEASE, __HIP_MEMORY_SCOPE_AGENT);
    } else {
      long long t0 = clock64();
      while (__hip_atomic_load(phs, __ATOMIC_ACQUIRE, __HIP_MEMORY_SCOPE_AGENT) < ph) {
        if (clock64() - t0 > 5000000LL) break;   // ~2ms bail: fail visibly, no hang
      }
    }
    __threadfence();
  }
  __syncthreads();
}

// ---------------- mega kernel: 32 layers, 3 phases each --------------------
struct MegaP {
  const __bf16 *WIN, *WXP, *WOUT;
  const float *cw, *cb, *dtw, *dtb, *A2v, *dsk, *lnw, *lnb;
  float *X; __bf16 *H; __bf16 *XZ; float *PART; float *SS; int *BAR;
};

__global__ __launch_bounds__(512, 4) void mamba_mega(MegaP P) {
  __shared__ __align__(16) char sMem[69888];
  __bf16* const sXC  = (__bf16*)sMem;               // P2 bf16 [16][512] swz
  __bf16* const sY   = (__bf16*)sMem;               // P3 [16][520] (aliases sXC)
  float*  const sXCf = (float*)(sMem + 16640);      // [16][512] f32 conv+silu
  float*  const sDBC = (float*)(sMem + 49408);      // [16][48]
  __bf16* const sB3  = (__bf16*)(sMem + 52480);     // [256][32] Wout tile
  float*  const sSum = (float*)(sMem + 68864);      // [8][16]
  float*  const sSq  = (float*)(sMem + 69376);      // [8][16]
  __bf16* const sA1  = (__bf16*)sMem;               // P1 A [128][32]
  __bf16* const sB1  = (__bf16*)(sMem + 8192);      // P1 B [128][32]

  const int tid = threadIdx.x;
  const int bid = blockIdx.x;
  const int c   = bid >> 5, b = bid & 31;           // P2/P3 chunk mapping
  const int bl0 = b * 256 + c * 16;
  const int bm0 = (bid >> 3) << 7;                  // P1 tile mapping
  const int bn0 = (bid & 7) << 7;
  const int lane = tid & 63, wv = tid >> 6;
  const int lr = lane & 15, lk = lane >> 4;
  int ph = 0;

  for (int l = 0; l < 32; ++l) {
    const __bf16* Wi  = P.WIN  + (size_t)l * 262144;
    const __bf16* Wx  = P.WXP  + (size_t)l * 24576;
    const __bf16* Wo  = P.WOUT + (size_t)l * 131072;
    const float* cwL  = P.cw  + (size_t)l * 2048;
    const float* cbL  = P.cb  + (size_t)l * 512;
    const float* dtwL = P.dtw + (size_t)l * 8192;
    const float* dtbL = P.dtb + (size_t)l * 512;
    const float* A2L  = P.A2v + (size_t)l * 8192;
    const float* dskL = P.dsk + (size_t)l * 512;
    const int lnx = (l + 1 < 32) ? l + 1 : 31;
    const float* lnwL = P.lnw + (size_t)lnx * 256;
    const float* lnbL = P.lnb + (size_t)lnx * 256;

    // ---------- P1: XZ = H @ Win^T (128x128 tile, 8 waves) ----------
    {
      const int wm  = (wv >> 2) << 6;
      const int wnc = (((wv >> 1) & 1) << 6) + ((wv & 1) << 5);
      v4f acc[4][2] = {};
      const int r0 = tid >> 2, c0 = (tid & 3) << 3;
      const int wbase = (tid & ~63) << 3;
      const __bf16* gA = P.H + (size_t)(bm0 + r0) * 256 + c0;
      const __bf16* gB = Wi  + (size_t)(bn0 + r0) * 256 + c0;
      for (int kk = 0; kk < 256; kk += 32) {
        async_copy16(gA + kk, sA1 + wbase);
        async_copy16(gB + kk, sB1 + wbase);
        __syncthreads();
        v8bf af[4], bfr[2];
        #pragma unroll
        for (int i = 0; i < 4; ++i)
          af[i] = *(const v8bf*)(sA1 + ((wm + i * 16 + lr) << 5) + (lk << 3));
        #pragma unroll
        for (int j = 0; j < 2; ++j)
          bfr[j] = *(const v8bf*)(sB1 + ((wnc + j * 16 + lr) << 5) + (lk << 3));
        #pragma unroll
        for (int i = 0; i < 4; ++i)
          #pragma unroll
          for (int j = 0; j < 2; ++j)
            acc[i][j] = __builtin_amdgcn_mfma_f32_16x16x32_bf16(af[i], bfr[j], acc[i][j], 0, 0, 0);
        __syncthreads();
      }
      #pragma unroll
      for (int i = 0; i < 4; ++i)
        #pragma unroll
        for (int j = 0; j < 2; ++j)
          #pragma unroll
          for (int v = 0; v < 4; ++v)
            P.XZ[(size_t)(bm0 + wm + i * 16 + (lk << 2) + v) * 1024 +
                 (bn0 + wnc + j * 16 + lr)] = (__bf16)acc[i][j][v];
    }
    gbar(P.BAR, ++ph);

    // ---------- P2: conv+silu -> sXC/sXCf ; x_proj -> sDBC ; pass1 ----------
    {
      const int r = tid >> 5, ec = tid & 31;
      #pragma unroll
      for (int j = 0; j < 2; ++j) {
        const int e = (ec << 3) + (j << 8);
        v4f cw4[8];
        #pragma unroll
        for (int jj = 0; jj < 8; ++jj) cw4[jj] = *(const v4f*)(cwL + (size_t)(e + jj) * 4);
        float a[8];
        #pragma unroll
        for (int jj = 0; jj < 8; ++jj) a[jj] = cbL[e + jj];
        #pragma unroll
        for (int k = 0; k < 4; ++k) {
          if (c > 0 || r + k >= 3) {
            const v8bf xv = *(const v8bf*)(P.XZ + (size_t)(bl0 + r + k - 3) * 1024 + e);
            #pragma unroll
            for (int jj = 0; jj < 8; ++jj) a[jj] += bf(xv[jj]) * cw4[jj][k];
          }
        }
        v8bf outv; v4f f0, f1;
        #pragma unroll
        for (int jj = 0; jj < 8; ++jj) {
          const float s = a[jj] / (1.f + __expf(-a[jj]));
          outv[jj] = (__bf16)s;
          if (jj < 4) f0[jj] = s; else f1[jj - 4] = s;
        }
        const int cbk = (e >> 3) ^ (r & 7);
        *(v8bf*)(sXC + r * 512 + (cbk << 3)) = outv;
        *(v4f*)(sXCf + r * 512 + e)     = f0;
        *(v4f*)(sXCf + r * 512 + e + 4) = f1;
      }
      __syncthreads();
      if (tid < 192) {                               // x_proj MFMA (3 waves)
        const int w = tid >> 6;
        v4f acc = {};
        for (int kk = 0; kk < 512; kk += 32) {
          const v8bf bfr = *(const v8bf*)(Wx + (size_t)(w * 16 + lr) * 512 + kk + (lk << 3));
          const int cbk = (((kk >> 3) + lk) ^ (lr & 7));
          const v8bf af = *(const v8bf*)(sXC + lr * 512 + (cbk << 3));
          acc = __builtin_amdgcn_mfma_f32_16x16x32_bf16(af, bfr, acc, 0, 0, 0);
        }
        const int gc = w * 16 + lr;
        #pragma unroll
        for (int v = 0; v < 4; ++v)
          sDBC[((lk << 2) + v) * 48 + gc] = acc[v];
      }
      __syncthreads();
      if (c < 15) {                                  // pass1 -> PART/SS
        const int e = tid;
        v4f a2v[4], wd[4];
        #pragma unroll
        for (int q = 0; q < 4; ++q) {
          a2v[q] = *(const v4f*)(A2L  + (size_t)e * 16 + q * 4);
          wd[q]  = *(const v4f*)(dtwL + (size_t)e * 16 + q * 4);
        }
        const float bias = dtbL[e];
        float part[16];
        #pragma unroll
        for (int n = 0; n < 16; ++n) part[n] = 0.f;
        float S = 0.f;
        for (int tt = 0; tt < 16; ++tt) {
          const v4f* dp = (const v4f*)(sDBC + tt * 48);
          float dtv = bias;
          {
            const v4f d0 = dp[0], d1 = dp[1], d2 = dp[2], d3 = dp[3];
            #pragma unroll
            for (int r2 = 0; r2 < 4; ++r2)
              dtv += d0[r2] * wd[0][r2] + d1[r2] * wd[1][r2] + d2[r2] * wd[2][r2] + d3[r2] * wd[3][r2];
          }
          dtv = (dtv > 20.f) ? dtv : log1pf(__expf(dtv));
          const float x = sXCf[tt * 512 + e];
          const float dtx = dtv * x;
          S += dtv;
          {
            const v4f bv0 = dp[4], bv1 = dp[5], bv2 = dp[6], bv3 = dp[7];
            #pragma unroll
            for (int v = 0; v < 4; ++v) {
              part[v]      = part[v]      * exp2f(dtv * a2v[0][v]) + dtx * bv0[v];
              part[4 + v]  = part[4 + v]  * exp2f(dtv * a2v[1][v]) + dtx * bv1[v];
              part[8 + v]  = part[8 + v]  * exp2f(dtv * a2v[2][v]) + dtx * bv2[v];
              part[12 + v] = part[12 + v] * exp2f(dtv * a2v[3][v]) + dtx * bv3[v];
            }
          }
        }
        const size_t o = (((size_t)c * 32 + b) * 512 + e) * 16;
        #pragma unroll
        for (int rq = 0; rq < 4; ++rq) {
          v4f p;
          #pragma unroll
          for (int v = 0; v < 4; ++v) p[v] = part[rq * 4 + v];
          *(v4f*)(P.PART + o + rq * 4) = p;
        }
        P.SS[((size_t)c * 32 + b) * 512 + e] = S;
      }
    }
    gbar(P.BAR, ++ph);

    // ---------- P3: prefix + scan2 + gate + out_proj + resid + LN ----------
    {
      const int e = tid;
      v4f a2v[4], wd[4];
      #pragma unroll
      for (int q = 0; q < 4; ++q) {
        a2v[q] = *(const v4f*)(A2L  + (size_t)e * 16 + q * 4);
        wd[q]  = *(const v4f*)(dtwL + (size_t)e * 16 + q * 4);
      }
      const float bias = dtbL[e];
      const float Dsk  = dskL[e];
      float h[16];
      #pragma unroll
      for (int n = 0; n < 16; ++n) h[n] = 0.f;
      for (int cc = 0; cc < c; ++cc) {
        const float S  = P.SS[((size_t)cc * 32 + b) * 512 + e];
        const size_t o = (((size_t)cc * 32 + b) * 512 + e) * 16;
        #pragma unroll
        for (int rq = 0; rq < 4; ++rq) {
          const v4f p = *(const v4f*)(P.PART + o + rq * 4);
          #pragma unroll
          for (int v = 0; v < 4; ++v)
            h[rq * 4 + v] = h[rq * 4 + v] * exp2f(a2v[rq][v] * S) + p[v];
        }
      }
      for (int tt = 0; tt < 16; ++tt) {              // scan from LDS-resident state
        const float x = sXCf[tt * 512 + e];
        const v4f* dp = (const v4f*)(sDBC + tt * 48);
        float dtv = bias;
        {
          const v4f d0 = dp[0], d1 = dp[1], d2 = dp[2], d3 = dp[3];
          #pragma unroll
          for (int r2 = 0; r2 < 4; ++r2)
            dtv += d0[r2] * wd[0][r2] + d1[r2] * wd[1][r2] + d2[r2] * wd[2][r2] + d3[r2] * wd[3][r2];
        }
        dtv = (dtv > 20.f) ? dtv : log1pf(__expf(dtv));
        const float dtx = dtv * x;
        float y = 0.f;
        {
          const v4f bv0 = dp[4], bv1 = dp[5], bv2 = dp[6], bv3 = dp[7];
          const v4f cv0 = dp[8], cv1 = dp[9], cv2 = dp[10], cv3 = dp[11];
          #pragma unroll
          for (int v = 0; v < 4; ++v) {
            h[v]      = h[v]      * exp2f(dtv * a2v[0][v]) + dtx * bv0[v];  y += h[v]      * cv0[v];
            h[4 + v]  = h[4 + v]  * exp2f(dtv * a2v[1][v]) + dtx * bv1[v];  y += h[4 + v]  * cv1[v];
            h[8 + v]  = h[8 + v]  * exp2f(dtv * a2v[2][v]) + dtx * bv2[v];  y += h[8 + v]  * cv2[v];
            h[12 + v] = h[12 + v] * exp2f(dtv * a2v[3][v]) + dtx * bv3[v];  y += h[12 + v] * cv3[v];
          }
        }
        const float z  = bf(P.XZ[(size_t)(bl0 + tt) * 1024 + 512 + e]);
        const float sg = z / (1.f + __expf(-z));
        sY[tt * 520 + e] = (__bf16)((y + x * Dsk) * sg);
      }
      __syncthreads();

      // out_proj: C(16x256) = sY @ Wout^T; 8 waves x 32 cols; Wout staged
      const int wn = wv << 5;
      v4f acc[2] = {};
      for (int kk = 0; kk < 512; kk += 32) {
        async_copy16(Wo + (size_t)(tid >> 2) * 512 + ((tid & 3) << 3) + kk,
                     sB3 + ((tid & ~63) << 3));
        async_copy16(Wo + (size_t)(128 + (tid >> 2)) * 512 + ((tid & 3) << 3) + kk,
                     sB3 + 4096 + ((tid & ~63) << 3));
        __syncthreads();
        const v8bf af = *(const v8bf*)(sY + lr * 520 + kk + (lk << 3));
        #pragma unroll
        for (int j = 0; j < 2; ++j) {
          const v8bf bfr = *(const v8bf*)(sB3 + ((wn + j * 16 + lr) << 5) + (lk << 3));
          acc[j] = __builtin_amdgcn_mfma_f32_16x16x32_bf16(af, bfr, acc[j], 0, 0, 0);
        }
        __syncthreads();
      }

      float s2[4], q2[4];
      #pragma unroll
      for (int v = 0; v < 4; ++v) {
        const int gr = bl0 + (lk << 2) + v;
        float s = 0.f, q = 0.f;
        #pragma unroll
        for (int j = 0; j < 2; ++j) {
          const int gc = wn + j * 16 + lr;
          float val = P.X[(size_t)gr * 256 + gc] + acc[j][v];
          acc[j][v] = val;
          s += val; q += val * val;
        }
        #pragma unroll
        for (int o = 8; o > 0; o >>= 1) { s += __shfl_xor(s, o); q += __shfl_xor(q, o); }
        s2[v] = s; q2[v] = q;
      }
      if (lr == 0) {
        #pragma unroll
        for (int v = 0; v < 4; ++v) {
          const int row = (lk << 2) + v;
          sSum[wv * 16 + row] = s2[v];
          sSq[wv * 16 + row]  = q2[v];
        }
      }
      __syncthreads();
      #pragma unroll
      for (int v = 0; v < 4; ++v) {
        const int row = (lk << 2) + v;
        float S = 0.f, Q = 0.f;
        #pragma unroll
        for (int ww = 0; ww < 8; ++ww) { S += sSum[ww * 16 + row]; Q += sSq[ww * 16 + row]; }
        const float mu   = S * (1.f / 256.f);
        const float var  = Q * (1.f / 256.f) - mu * mu;
        const float rinv = rsqrtf(var + 1e-5f);
        const int gr = bl0 + row;
        #pragma unroll
        for (int j = 0; j < 2; ++j) {
          const int gc = wn + j * 16 + lr;
          const float val = acc[j][v];
          P.X[(size_t)gr * 256 + gc] = val;
          P.H[(size_t)gr * 256 + gc] = (__bf16)((val - mu) * rinv * lnwL[gc] + lnbL[gc]);
        }
      }
      __syncthreads();
    }
    gbar(P.BAR, ++ph);
  }
}

extern "C" void kernel_launch(void* const* d_in, const int* in_sizes, int n_in,
                              void* d_out, int out_size, void* d_ws, size_t ws_size,
                              hipStream_t stream) {
  const int*   tok  = (const int*)d_in[0];
  const float* emb  = (const float*)d_in[1];
  const float* lnw  = (const float*)d_in[2];
  const float* lnb  = (const float*)d_in[3];
  const float* inw  = (const float*)d_in[4];
  const float* cw   = (const float*)d_in[5];
  const float* cb   = (const float*)d_in[6];
  const float* xpw  = (const float*)d_in[7];
  const float* dtw  = (const float*)d_in[8];
  const float* dtb  = (const float*)d_in[9];
  const float* alog = (const float*)d_in[10];
  const float* dsk  = (const float*)d_in[11];
  const float* outw = (const float*)d_in[12];
  const float* W1   = (const float*)d_in[13];
  const float* b1   = (const float*)d_in[14];
  const float* W2   = (const float*)d_in[15];
  const float* b2   = (const float*)d_in[16];

  char* ws = (char*)d_ws;
  __bf16* WIN   = (__bf16*)(ws + OFF_WIN);
  __bf16* WXP   = (__bf16*)(ws + OFF_WXP);
  __bf16* WOUT  = (__bf16*)(ws + OFF_WOUT);
  __bf16* WW1   = (__bf16*)(ws + OFF_WW1);
  __bf16* WW2   = (__bf16*)(ws + OFF_WW2);
  float*  X     = (float*)(ws + OFF_X);
  __bf16* H     = (__bf16*)(ws + OFF_H);
  __bf16* XZ    = (__bf16*)(ws + OFF_XZ);
  float*  PART  = (float*)(ws + OFF_PART);
  float*  SS    = (float*)(ws + OFF_SS);
  float*  A2    = (float*)(ws + OFF_A2);
  int*    BAR   = (int*)(ws + OFF_BAR);
  __bf16* XB    = (__bf16*)(ws + OFF_PART);                 // head-phase aliases
  __bf16* HH    = (__bf16*)(ws + OFF_PART + 8388608);

  f2b_multi<<<70656, 256, 0, stream>>>(inw, xpw, outw, W1, W2, alog, ws);
  embed_ln_k<<<8192, 256, 0, stream>>>(tok, emb, lnw, lnb, X, H);

  MegaP mp;
  mp.WIN = WIN; mp.WXP = WXP; mp.WOUT = WOUT;
  mp.cw = cw; mp.cb = cb; mp.dtw = dtw; mp.dtb = dtb;
  mp.A2v = A2; mp.dsk = dsk; mp.lnw = lnw; mp.lnb = lnb;
  mp.X = X; mp.H = H; mp.XZ = XZ; mp.PART = PART; mp.SS = SS; mp.BAR = BAR;
  mamba_mega<<<512, 512, 0, stream>>>(mp);

  f2b_k<<<8192, 256, 0, stream>>>(X, XB);
  gemm_bt<1><<<dim3(8, 64), 256, 0, stream>>>(XB, WW1, HH, b1, 8192, 1024, 256);
  gemm_bt<2><<<dim3(32, 64), 256, 0, stream>>>(HH, WW2, (float*)d_out, b2, 8192, 4096, 1024);
}

// Round 6
// 4126.283 us; speedup vs baseline: 3.4393x; 3.4393x over previous
//
#include <hip/hip_runtime.h>
#include <hip/hip_bf16.h>
#include <cstdint>
#include <cstddef>

// ---------------------------------------------------------------------------
// Model dims: NL=32, D=256, DI=512, N=16, R=16, K=4, V=4096, FF=1024, B=32, L=256
// R9: 2 dispatches/layer, XZ eliminated. in_proj split row-locally:
//   K2 computes xm(19 rows w/ halo, M-pad 48) + conv+silu + x_proj + pass1;
//   K3 computes z(32 rows) + prefix + scan2 + gate + out_proj + resid + LN.
//   All GEMM B-operands staged via global_load_lds (R6's direct-L2 mistake
//   fixed); A/B LDS reads XOR-swizzled (gemm_bt's 8.4M-conflict lesson).
//   All cross-block flow via dispatch boundaries, same-XCD (bid%8=b%8).
//   R8 lesson: grid barriers cost >100us on MI355X — never again.
// ---------------------------------------------------------------------------

typedef __bf16 v8bf __attribute__((ext_vector_type(8)));
typedef float  v4f  __attribute__((ext_vector_type(4)));

__device__ __forceinline__ void async_copy16(const void* g, void* l) {
  __builtin_amdgcn_global_load_lds((const __attribute__((address_space(1))) void*)g,
                                   (__attribute__((address_space(3))) void*)l, 16, 0, 0);
}

__device__ __forceinline__ float bf(__bf16 v) { return (float)v; }

// ---------------- workspace layout (bytes) ---------------------------------
constexpr size_t OFF_WIN  = 0;           // bf16 32*1024*256   end 16,777,216
constexpr size_t OFF_WXP  = 16777216;    // bf16 32*48*512     end 18,350,080
constexpr size_t OFF_WOUT = 18350080;    // bf16 32*256*512    end 26,738,688
constexpr size_t OFF_WW1  = 26738688;    // bf16 1024*256      end 27,262,976
constexpr size_t OFF_WW2  = 27262976;    // bf16 4096*1024     end 35,651,584
constexpr size_t OFF_X    = 35651584;    // f32  8192*256      end 44,040,192
constexpr size_t OFF_H    = 44040192;    // bf16 8192*256      end 48,234,496
constexpr size_t OFF_XC   = 48234496;    // bf16 8192*512      end 56,623,104
constexpr size_t OFF_DBC  = 65011712;    // f32  8192*48       end 66,584,576
constexpr size_t OFF_PART = 66584576;    // f32  7*32*512*16   end 73,924,608
constexpr size_t OFF_SS   = 82313216;    // f32  7*32*512      end 82,771,200
constexpr size_t OFF_A2   = 83296256;    // f32  32*512*16     end 84,344,832
// head aliases: XB -> OFF_PART, HH -> OFF_PART+8388608 (covers SS/A2 — dead at
// head time; A2 recomputed by f2b_multi each replay). Proven pattern (R7).

// ---------------- batched f32 -> bf16 weight conversion + A2 table ---------
__global__ __launch_bounds__(256)
void f2b_multi(const float* __restrict__ s0, const float* __restrict__ s1,
               const float* __restrict__ s2, const float* __restrict__ s3,
               const float* __restrict__ s4, const float* __restrict__ s5,
               char* __restrict__ ws) {
  size_t i = (size_t)blockIdx.x * 256 + threadIdx.x;
  if (i < 8388608) { ((__bf16*)(ws + OFF_WIN))[i] = (__bf16)s0[i]; return; }
  i -= 8388608;
  if (i < 786432)  { ((__bf16*)(ws + OFF_WXP))[i] = (__bf16)s1[i]; return; }
  i -= 786432;
  if (i < 4194304) { ((__bf16*)(ws + OFF_WOUT))[i] = (__bf16)s2[i]; return; }
  i -= 4194304;
  if (i < 262144)  { ((__bf16*)(ws + OFF_WW1))[i] = (__bf16)s3[i]; return; }
  i -= 262144;
  if (i < 4194304) { ((__bf16*)(ws + OFF_WW2))[i] = (__bf16)s4[i]; return; }
  i -= 4194304;
  ((float*)(ws + OFF_A2))[i] = -1.4426950408889634f * __expf(s5[i]);
}

__global__ __launch_bounds__(256) void f2b_k(const float* __restrict__ X,
                                             __bf16* __restrict__ O) {
  size_t i = (size_t)blockIdx.x * 256 + threadIdx.x;
  O[i] = (__bf16)X[i];
}

// ---------------- embed + layer-0 LN ---------------------------------------
__global__ __launch_bounds__(256)
void embed_ln_k(const int* __restrict__ tok, const float* __restrict__ emb,
                const float* __restrict__ w, const float* __restrict__ b,
                float* __restrict__ X, __bf16* __restrict__ H) {
  int row = blockIdx.x;
  int t   = threadIdx.x;
  float v = emb[(size_t)tok[row] * 256 + t];
  X[(size_t)row * 256 + t] = v;
  float s = v, q = v * v;
  #pragma unroll
  for (int o = 32; o > 0; o >>= 1) { s += __shfl_xor(s, o); q += __shfl_xor(q, o); }
  __shared__ float ss[4], qq[4];
  int wv = t >> 6;
  if ((t & 63) == 0) { ss[wv] = s; qq[wv] = q; }
  __syncthreads();
  s = ss[0] + ss[1] + ss[2] + ss[3];
  q = qq[0] + qq[1] + qq[2] + qq[3];
  float mu  = s * (1.f / 256.f);
  float var = q * (1.f / 256.f) - mu * mu;
  float r   = rsqrtf(var + 1e-5f);
  H[(size_t)row * 256 + t] = (__bf16)((v - mu) * r * w[t] + b[t]);
}

// ---------------- generic MFMA bf16 GEMM (head only) -----------------------
template <int EPI>
__global__ __launch_bounds__(256, 2)
void gemm_bt(const __bf16* __restrict__ A, const __bf16* __restrict__ W,
             void* outp, const float* __restrict__ bias, int M, int N, int K) {
  __shared__ __align__(16) __bf16 sA[128 * 32];
  __shared__ __align__(16) __bf16 sB[128 * 32];
  const int tid  = threadIdx.x;
  const int bm0  = blockIdx.y << 7;
  const int bn0  = blockIdx.x << 7;
  const int lane = tid & 63;
  const int wv   = tid >> 6;
  const int wm   = (wv >> 1) << 6;
  const int wn   = (wv & 1) << 6;
  const int lr   = lane & 15;
  const int lk   = lane >> 4;

  v4f acc[4][4] = {};

  const int r0 = tid >> 2;
  const int c0 = (tid & 3) << 3;
  const int wbase = (tid & ~63) << 3;

  const __bf16* gA0 = A + (size_t)(bm0 + r0) * K + c0;
  const __bf16* gA1 = A + (size_t)(bm0 + 64 + r0) * K + c0;
  const __bf16* gB0 = W + (size_t)(bn0 + r0) * K + c0;
  const __bf16* gB1 = W + (size_t)(bn0 + 64 + r0) * K + c0;

  for (int kk = 0; kk < K; kk += 32) {
    async_copy16(gA0 + kk, sA + wbase);
    async_copy16(gA1 + kk, sA + 2048 + wbase);
    async_copy16(gB0 + kk, sB + wbase);
    async_copy16(gB1 + kk, sB + 2048 + wbase);
    __syncthreads();
    v8bf af[4], bfr[4];
    #pragma unroll
    for (int i = 0; i < 4; ++i)
      af[i] = *(const v8bf*)(sA + ((wm + i * 16 + lr) << 5) + (lk << 3));
    #pragma unroll
    for (int j = 0; j < 4; ++j)
      bfr[j] = *(const v8bf*)(sB + ((wn + j * 16 + lr) << 5) + (lk << 3));
    #pragma unroll
    for (int i = 0; i < 4; ++i)
      #pragma unroll
      for (int j = 0; j < 4; ++j)
        acc[i][j] = __builtin_amdgcn_mfma_f32_16x16x32_bf16(af[i], bfr[j], acc[i][j], 0, 0, 0);
    __syncthreads();
  }

  #pragma unroll
  for (int i = 0; i < 4; ++i) {
    #pragma unroll
    for (int j = 0; j < 4; ++j) {
      int gc = bn0 + wn + j * 16 + lr;
      #pragma unroll
      for (int v = 0; v < 4; ++v) {
        int gr = bm0 + wm + i * 16 + (lk << 2) + v;
        float val = acc[i][j][v];
        size_t idx = (size_t)gr * N + gc;
        if (EPI == 0) {
          ((__bf16*)outp)[idx] = (__bf16)val;
        } else if (EPI == 1) {
          val += bias[gc]; val = fmaxf(val, 0.f);
          ((__bf16*)outp)[idx] = (__bf16)val;
        } else {
          ((float*)outp)[idx] = val + bias[gc];
        }
      }
    }
  }
}

// ---------------- K2: xm in_proj + conv+silu + x_proj + pass1 --------------
// Grid 256 = chunk c (bid>>5, 0..7) x batch b (bid&31); 512 thr; 1 blk/CU.
// xm GEMM: M=48 (19 valid rows: 3 halo + 32 own), N=512, K=256. B staged via
// global_load_lds (swizzled source); A (H rows) reg-staged swizzled.
__global__ __launch_bounds__(512, 2)
void k2_inconv_k(const __bf16* __restrict__ H, const __bf16* __restrict__ Wi,
                 const float* __restrict__ cw, const float* __restrict__ cb,
                 const __bf16* __restrict__ Wxp,
                 const float* __restrict__ dtw, const float* __restrict__ dtb,
                 const float* __restrict__ A2,
                 __bf16* __restrict__ XC, float* __restrict__ DBC,
                 float* __restrict__ PART, float* __restrict__ SS) {
  __shared__ __align__(16) char sm[93184];
  __bf16* const sH   = (__bf16*)sm;             // [48][256] swz (rows 0..34 valid)
  __bf16* const sB   = (__bf16*)(sm + 24576);   // [512][32] staged Win k-tile
  __bf16* const sXM  = (__bf16*)(sm + 57344);   // [35][512] xm (row m = seq bl0-3+m)
  __bf16* const sXC  = (__bf16*)(sm + 24576);   // [32][512] swz (alias sB, after GEMM)
  float*  const sDBC = (float*)sm;              // [32][48]  (alias sH, after GEMM)

  const int tid = threadIdx.x;
  const int c   = blockIdx.x >> 5;
  const int b   = blockIdx.x & 31;
  const int bl0 = b * 256 + c * 32;
  const int lane = tid & 63, wv = tid >> 6;
  const int lr = lane & 15, lk = lane >> 4;

  // -- stage A: H rows bl0-3..bl0+31 -> sH swizzled (16B-chunk ^ row&7)
  #pragma unroll
  for (int rnd = 0; rnd < 3; ++rnd) {
    const int q = rnd * 512 + tid;
    if (q < 1120) {
      const int row = q >> 5, cc = q & 31;
      int hr = bl0 - 3 + row; if (hr < 0) hr = 0;    // clamp; zeroed in epilogue
      const v8bf hv = *(const v8bf*)(H + (size_t)hr * 256 + (cc << 3));
      *(v8bf*)(sH + row * 256 + ((cc ^ (row & 7)) << 3)) = hv;
    }
  }
  __syncthreads();

  // -- xm GEMM: sXM(35x512) = sH(48x256) @ Wi(512x256)^T
  const int wn = wv << 6;
  {
    v4f acc[3][4] = {};
    for (int kk = 0; kk < 256; kk += 32) {
      #pragma unroll
      for (int rnd = 0; rnd < 4; ++rnd) {            // stage B 512x32 (swz source)
        const int q = rnd * 512 + tid;
        const int n = q >> 2, cbs = (q & 3) ^ (n & 3);
        async_copy16(Wi + (size_t)n * 256 + kk + (cbs << 3), sB + ((q & ~63) << 3));
      }
      __syncthreads();
      v8bf af[3], bfr[4];
      #pragma unroll
      for (int i = 0; i < 3; ++i) {
        const int row = i * 16 + lr;
        af[i] = *(const v8bf*)(sH + row * 256 + ((((kk >> 3) + lk) ^ (row & 7)) << 3));
      }
      #pragma unroll
      for (int j = 0; j < 4; ++j) {
        const int n = wn + j * 16 + lr;
        bfr[j] = *(const v8bf*)(sB + n * 32 + ((lk ^ (n & 3)) << 3));
      }
      #pragma unroll
      for (int i = 0; i < 3; ++i)
        #pragma unroll
        for (int j = 0; j < 4; ++j)
          acc[i][j] = __builtin_amdgcn_mfma_f32_16x16x32_bf16(af[i], bfr[j], acc[i][j], 0, 0, 0);
      __syncthreads();
    }
    #pragma unroll
    for (int i = 0; i < 3; ++i)
      #pragma unroll
      for (int v = 0; v < 4; ++v) {
        const int row = i * 16 + (lk << 2) + v;
        if (row < 35) {
          #pragma unroll
          for (int j = 0; j < 4; ++j) {
            float val = acc[i][j][v];
            if (c == 0 && row < 3) val = 0.f;        // causal zero-pad
            sXM[row * 512 + wn + j * 16 + lr] = (__bf16)val;
          }
        }
      }
  }
  __syncthreads();

  // -- conv(K=4)+SiLU: sXM -> sXC (swz) + XC global (L2-local consumer = K3)
  {
    const int r = tid >> 4, ec = tid & 15;
    #pragma unroll
    for (int j = 0; j < 4; ++j) {
      const int e = (ec << 3) + (j << 7);
      v4f cw4[8];
      #pragma unroll
      for (int jj = 0; jj < 8; ++jj) cw4[jj] = *(const v4f*)(cw + (size_t)(e + jj) * 4);
      float a[8];
      #pragma unroll
      for (int jj = 0; jj < 8; ++jj) a[jj] = cb[e + jj];
      #pragma unroll
      for (int k = 0; k < 4; ++k) {
        const v8bf xv = *(const v8bf*)(sXM + (r + k) * 512 + e);
        #pragma unroll
        for (int jj = 0; jj < 8; ++jj) a[jj] += bf(xv[jj]) * cw4[jj][k];
      }
      v8bf outv;
      #pragma unroll
      for (int jj = 0; jj < 8; ++jj) {
        const float s = a[jj] / (1.f + __expf(-a[jj]));
        outv[jj] = (__bf16)s;
      }
      const int cbk = (e >> 3) ^ (r & 7);
      *(v8bf*)(sXC + r * 512 + (cbk << 3)) = outv;
      *(v8bf*)(XC + (size_t)(bl0 + r) * 512 + e) = outv;
    }
  }
  __syncthreads();

  // -- x_proj: sDBC(32x48) = sXC @ Wxp^T (3 waves; Wxp from L2 — R5-proven)
  if (tid < 192) {
    const int w = tid >> 6;
    v4f accp[2] = {};
    for (int kk = 0; kk < 512; kk += 32) {
      const v8bf bfr = *(const v8bf*)(Wxp + (size_t)(w * 16 + lr) * 512 + kk + (lk << 3));
      #pragma unroll
      for (int i = 0; i < 2; ++i) {
        const int row = i * 16 + lr;
        const int cbk = (((kk >> 3) + lk) ^ (row & 7));
        const v8bf af = *(const v8bf*)(sXC + row * 512 + (cbk << 3));
        accp[i] = __builtin_amdgcn_mfma_f32_16x16x32_bf16(af, bfr, accp[i], 0, 0, 0);
      }
    }
    const int gc = w * 16 + lr;
    #pragma unroll
    for (int i = 0; i < 2; ++i)
      #pragma unroll
      for (int v = 0; v < 4; ++v)
        sDBC[(i * 16 + (lk << 2) + v) * 48 + gc] = accp[i][v];
  }
  __syncthreads();

  // -- DBC writeback (6KB; L2-local)
  if (tid < 384)
    *(v4f*)(DBC + (size_t)bl0 * 48 + tid * 4) = *(const v4f*)(sDBC + tid * 4);

  // -- pass1: per-chunk (part[16], S) for chunks 0..6
  if (c < 7) {
    const int e = tid;
    v4f a2v[4], wd[4];
    #pragma unroll
    for (int q = 0; q < 4; ++q) {
      a2v[q] = *(const v4f*)(A2  + (size_t)e * 16 + q * 4);
      wd[q]  = *(const v4f*)(dtw + (size_t)e * 16 + q * 4);
    }
    const float bias = dtb[e];
    float part[16];
    #pragma unroll
    for (int n = 0; n < 16; ++n) part[n] = 0.f;
    float S = 0.f;
    for (int tt = 0; tt < 32; ++tt) {
      const v4f* dp = (const v4f*)(sDBC + tt * 48);
      float dtv = bias;
      {
        const v4f d0 = dp[0], d1 = dp[1], d2 = dp[2], d3 = dp[3];
        #pragma unroll
        for (int r2 = 0; r2 < 4; ++r2)
          dtv += d0[r2] * wd[0][r2] + d1[r2] * wd[1][r2] + d2[r2] * wd[2][r2] + d3[r2] * wd[3][r2];
      }
      dtv = (dtv > 20.f) ? dtv : log1pf(__expf(dtv));
      const float x = bf(sXC[tt * 512 + (((e >> 3) ^ (tt & 7)) << 3) + (e & 7)]);
      const float dtx = dtv * x;
      S += dtv;
      {
        const v4f bv0 = dp[4], bv1 = dp[5], bv2 = dp[6], bv3 = dp[7];
        #pragma unroll
        for (int v = 0; v < 4; ++v) {
          part[v]      = part[v]      * exp2f(dtv * a2v[0][v]) + dtx * bv0[v];
          part[4 + v]  = part[4 + v]  * exp2f(dtv * a2v[1][v]) + dtx * bv1[v];
          part[8 + v]  = part[8 + v]  * exp2f(dtv * a2v[2][v]) + dtx * bv2[v];
          part[12 + v] = part[12 + v] * exp2f(dtv * a2v[3][v]) + dtx * bv3[v];
        }
      }
    }
    const size_t o = (((size_t)c * 32 + b) * 512 + e) * 16;
    #pragma unroll
    for (int rq = 0; rq < 4; ++rq) {
      v4f p;
      #pragma unroll
      for (int v = 0; v < 4; ++v) p[v] = part[rq * 4 + v];
      *(v4f*)(PART + o + rq * 4) = p;
    }
    SS[((size_t)c * 32 + b) * 512 + e] = S;
  }
}

// ---------------- K3: z in_proj + prefix + scan2 + gate + out_proj + LN ----
// Grid 256 = (c,b); 512 thr. z GEMM M=32 exact. XC/DBC/PART/SS from K2
// (dispatch boundary; same-XCD L2). In-place H update (reads staged first).
__global__ __launch_bounds__(512, 2)
void k3_zscan_k(const __bf16* H, const __bf16* __restrict__ Wz,
                const __bf16* __restrict__ XC, const float* __restrict__ DBC,
                const float* __restrict__ dtw, const float* __restrict__ dtb,
                const float* __restrict__ A2, const float* __restrict__ Dskip,
                const float* __restrict__ PART, const float* __restrict__ SS,
                const __bf16* __restrict__ Wout,
                const float* __restrict__ lnw, const float* __restrict__ lnb,
                float* __restrict__ X, __bf16* Hout) {
  __shared__ __align__(16) char sm[83968];
  __bf16* const sH   = (__bf16*)sm;             // [32][256] swz
  __bf16* const sBz  = (__bf16*)(sm + 16384);   // [512][32] staged Wz k-tile
  __bf16* const sY   = (__bf16*)sm;             // [32][520] (alias, after z-GEMM)
  __bf16* const sB3  = (__bf16*)(sm + 33280);   // [256][32] Wout tile (alias)
  float*  const sSum = (float*)(sm + 49664);    // [4][32]
  float*  const sSq  = (float*)(sm + 50176);    // [4][32]
  __bf16* const sZ   = (__bf16*)(sm + 50688);   // [32][520]

  const int tid = threadIdx.x;
  const int c   = blockIdx.x >> 5;
  const int b   = blockIdx.x & 31;
  const int bl0 = b * 256 + c * 32;
  const int lane = tid & 63, wv = tid >> 6;
  const int lr = lane & 15, lk = lane >> 4;

  // -- stage A: H rows bl0..bl0+31 -> sH swizzled
  #pragma unroll
  for (int rnd = 0; rnd < 2; ++rnd) {
    const int q = rnd * 512 + tid;
    const int row = q >> 5, cc = q & 31;
    const v8bf hv = *(const v8bf*)(H + (size_t)(bl0 + row) * 256 + (cc << 3));
    *(v8bf*)(sH + row * 256 + ((cc ^ (row & 7)) << 3)) = hv;
  }
  __syncthreads();

  // -- z GEMM: sZ(32x512) = sH(32x256) @ Wz(512x256)^T
  const int wn = wv << 6;
  {
    v4f acc[2][4] = {};
    for (int kk = 0; kk < 256; kk += 32) {
      #pragma unroll
      for (int rnd = 0; rnd < 4; ++rnd) {
        const int q = rnd * 512 + tid;
        const int n = q >> 2, cbs = (q & 3) ^ (n & 3);
        async_copy16(Wz + (size_t)n * 256 + kk + (cbs << 3), sBz + ((q & ~63) << 3));
      }
      __syncthreads();
      v8bf af[2], bfr[4];
      #pragma unroll
      for (int i = 0; i < 2; ++i) {
        const int row = i * 16 + lr;
        af[i] = *(const v8bf*)(sH + row * 256 + ((((kk >> 3) + lk) ^ (row & 7)) << 3));
      }
      #pragma unroll
      for (int j = 0; j < 4; ++j) {
        const int n = wn + j * 16 + lr;
        bfr[j] = *(const v8bf*)(sBz + n * 32 + ((lk ^ (n & 3)) << 3));
      }
      #pragma unroll
      for (int i = 0; i < 2; ++i)
        #pragma unroll
        for (int j = 0; j < 4; ++j)
          acc[i][j] = __builtin_amdgcn_mfma_f32_16x16x32_bf16(af[i], bfr[j], acc[i][j], 0, 0, 0);
      __syncthreads();
    }
    #pragma unroll
    for (int i = 0; i < 2; ++i)
      #pragma unroll
      for (int v = 0; v < 4; ++v) {
        const int row = i * 16 + (lk << 2) + v;
        #pragma unroll
        for (int j = 0; j < 4; ++j)
          sZ[row * 520 + wn + j * 16 + lr] = (__bf16)acc[i][j][v];
      }
  }
  __syncthreads();

  // -- per-channel constants + chunk-prefix combine
  const int e = tid;
  v4f a2v[4], wd[4];
  #pragma unroll
  for (int q = 0; q < 4; ++q) {
    a2v[q] = *(const v4f*)(A2  + (size_t)e * 16 + q * 4);
    wd[q]  = *(const v4f*)(dtw + (size_t)e * 16 + q * 4);
  }
  const float bias = dtb[e];
  const float Dsk  = Dskip[e];
  float h[16];
  #pragma unroll
  for (int n = 0; n < 16; ++n) h[n] = 0.f;
  for (int cc = 0; cc < c; ++cc) {
    const float S  = SS[((size_t)cc * 32 + b) * 512 + e];
    const size_t o = (((size_t)cc * 32 + b) * 512 + e) * 16;
    #pragma unroll
    for (int rq = 0; rq < 4; ++rq) {
      const v4f p = *(const v4f*)(PART + o + rq * 4);
      #pragma unroll
      for (int v = 0; v < 4; ++v)
        h[rq * 4 + v] = h[rq * 4 + v] * exp2f(a2v[rq][v] * S) + p[v];
    }
  }

  // -- in-chunk recurrence + C-dot + skip + gate -> sY
  for (int tt = 0; tt < 32; ++tt) {
    const float x = bf(XC[(size_t)(bl0 + tt) * 512 + e]);
    const v4f* dp = (const v4f*)(DBC + (size_t)(bl0 + tt) * 48);
    float dtv = bias;
    {
      const v4f d0 = dp[0], d1 = dp[1], d2 = dp[2], d3 = dp[3];
      #pragma unroll
      for (int r2 = 0; r2 < 4; ++r2)
        dtv += d0[r2] * wd[0][r2] + d1[r2] * wd[1][r2] + d2[r2] * wd[2][r2] + d3[r2] * wd[3][r2];
    }
    dtv = (dtv > 20.f) ? dtv : log1pf(__expf(dtv));
    const float dtx = dtv * x;
    float y = 0.f;
    {
      const v4f bv0 = dp[4], bv1 = dp[5], bv2 = dp[6], bv3 = dp[7];
      const v4f cv0 = dp[8], cv1 = dp[9], cv2 = dp[10], cv3 = dp[11];
      #pragma unroll
      for (int v = 0; v < 4; ++v) {
        h[v]      = h[v]      * exp2f(dtv * a2v[0][v]) + dtx * bv0[v];  y += h[v]      * cv0[v];
        h[4 + v]  = h[4 + v]  * exp2f(dtv * a2v[1][v]) + dtx * bv1[v];  y += h[4 + v]  * cv1[v];
        h[8 + v]  = h[8 + v]  * exp2f(dtv * a2v[2][v]) + dtx * bv2[v];  y += h[8 + v]  * cv2[v];
        h[12 + v] = h[12 + v] * exp2f(dtv * a2v[3][v]) + dtx * bv3[v];  y += h[12 + v] * cv3[v];
      }
    }
    const float z  = bf(sZ[tt * 520 + e]);
    const float sg = z / (1.f + __expf(-z));
    sY[tt * 520 + e] = (__bf16)((y + x * Dsk) * sg);
  }
  __syncthreads();

  // -- out_proj: C(32x256) = sY(32x512) @ Wout(256x512)^T, 8 waves, staged B
  const int wm = (wv & 1) << 4;
  const int wn3 = (wv >> 1) << 6;
  v4f acc3[4] = {};
  for (int kk = 0; kk < 512; kk += 32) {
    async_copy16(Wout + (size_t)(tid >> 2) * 512 + ((tid & 3) << 3) + kk,
                 sB3 + ((tid & ~63) << 3));
    async_copy16(Wout + (size_t)(128 + (tid >> 2)) * 512 + ((tid & 3) << 3) + kk,
                 sB3 + 4096 + ((tid & ~63) << 3));
    __syncthreads();
    const v8bf af = *(const v8bf*)(sY + (wm + lr) * 520 + kk + (lk << 3));
    #pragma unroll
    for (int j = 0; j < 4; ++j) {
      const v8bf bfr = *(const v8bf*)(sB3 + ((wn3 + j * 16 + lr) << 5) + (lk << 3));
      acc3[j] = __builtin_amdgcn_mfma_f32_16x16x32_bf16(af, bfr, acc3[j], 0, 0, 0);
    }
    __syncthreads();
  }

  // -- residual add + per-row LN stats
  float s2[4], q2[4];
  #pragma unroll
  for (int v = 0; v < 4; ++v) {
    const int gr = bl0 + wm + (lk << 2) + v;
    float s = 0.f, q = 0.f;
    #pragma unroll
    for (int j = 0; j < 4; ++j) {
      const int gc = wn3 + j * 16 + lr;
      float val = X[(size_t)gr * 256 + gc] + acc3[j][v];
      acc3[j][v] = val;
      s += val; q += val * val;
    }
    #pragma unroll
    for (int o = 8; o > 0; o >>= 1) { s += __shfl_xor(s, o); q += __shfl_xor(q, o); }
    s2[v] = s; q2[v] = q;
  }
  if (lr == 0) {
    #pragma unroll
    for (int v = 0; v < 4; ++v) {
      const int row = wm + (lk << 2) + v;
      sSum[(wv >> 1) * 32 + row] = s2[v];
      sSq[(wv >> 1) * 32 + row]  = q2[v];
    }
  }
  __syncthreads();
  #pragma unroll
  for (int v = 0; v < 4; ++v) {
    const int row = wm + (lk << 2) + v;
    const float S = sSum[row] + sSum[32 + row] + sSum[64 + row] + sSum[96 + row];
    const float Q = sSq[row]  + sSq[32 + row]  + sSq[64 + row]  + sSq[96 + row];
    const float mu   = S * (1.f / 256.f);
    const float var  = Q * (1.f / 256.f) - mu * mu;
    const float rinv = rsqrtf(var + 1e-5f);
    const int gr = bl0 + row;
    #pragma unroll
    for (int j = 0; j < 4; ++j) {
      const int gc = wn3 + j * 16 + lr;
      const float val = acc3[j][v];
      X[(size_t)gr * 256 + gc] = val;
      Hout[(size_t)gr * 256 + gc] = (__bf16)((val - mu) * rinv * lnw[gc] + lnb[gc]);
    }
  }
}

extern "C" void kernel_launch(void* const* d_in, const int* in_sizes, int n_in,
                              void* d_out, int out_size, void* d_ws, size_t ws_size,
                              hipStream_t stream) {
  const int*   tok  = (const int*)d_in[0];
  const float* emb  = (const float*)d_in[1];
  const float* lnw  = (const float*)d_in[2];
  const float* lnb  = (const float*)d_in[3];
  const float* inw  = (const float*)d_in[4];
  const float* cw   = (const float*)d_in[5];
  const float* cb   = (const float*)d_in[6];
  const float* xpw  = (const float*)d_in[7];
  const float* dtw  = (const float*)d_in[8];
  const float* dtb  = (const float*)d_in[9];
  const float* alog = (const float*)d_in[10];
  const float* dsk  = (const float*)d_in[11];
  const float* outw = (const float*)d_in[12];
  const float* W1   = (const float*)d_in[13];
  const float* b1   = (const float*)d_in[14];
  const float* W2   = (const float*)d_in[15];
  const float* b2   = (const float*)d_in[16];

  char* ws = (char*)d_ws;
  __bf16* WIN   = (__bf16*)(ws + OFF_WIN);
  __bf16* WXP   = (__bf16*)(ws + OFF_WXP);
  __bf16* WOUT  = (__bf16*)(ws + OFF_WOUT);
  __bf16* WW1   = (__bf16*)(ws + OFF_WW1);
  __bf16* WW2   = (__bf16*)(ws + OFF_WW2);
  float*  X     = (float*)(ws + OFF_X);
  __bf16* H     = (__bf16*)(ws + OFF_H);
  __bf16* XC    = (__bf16*)(ws + OFF_XC);
  float*  DBC   = (float*)(ws + OFF_DBC);
  float*  PART  = (float*)(ws + OFF_PART);
  float*  SS    = (float*)(ws + OFF_SS);
  float*  A2    = (float*)(ws + OFF_A2);
  __bf16* XB    = (__bf16*)(ws + OFF_PART);                 // head-phase aliases
  __bf16* HH    = (__bf16*)(ws + OFF_PART + 8388608);

  f2b_multi<<<70656, 256, 0, stream>>>(inw, xpw, outw, W1, W2, alog, ws);
  embed_ln_k<<<8192, 256, 0, stream>>>(tok, emb, lnw, lnb, X, H);

  for (int l = 0; l < 32; ++l) {
    const __bf16* Wi_l   = WIN  + (size_t)l * 262144;          // xm rows 0..511
    const __bf16* Wz_l   = WIN  + (size_t)l * 262144 + 131072; // z rows 512..1023
    const float*  cw_l   = cw   + (size_t)l * 2048;
    const float*  cb_l   = cb   + (size_t)l * 512;
    const __bf16* xpw_l  = WXP  + (size_t)l * 24576;
    const float*  dtw_l  = dtw  + (size_t)l * 8192;
    const float*  dtb_l  = dtb  + (size_t)l * 512;
    const float*  A2_l   = A2   + (size_t)l * 8192;
    const float*  dsk_l  = dsk  + (size_t)l * 512;
    const __bf16* outw_l = WOUT + (size_t)l * 131072;
    const int lnx = (l + 1 < 32) ? l + 1 : 31;

    k2_inconv_k<<<256, 512, 0, stream>>>(H, Wi_l, cw_l, cb_l, xpw_l, dtw_l, dtb_l,
                                         A2_l, XC, DBC, PART, SS);
    k3_zscan_k<<<256, 512, 0, stream>>>(H, Wz_l, XC, DBC, dtw_l, dtb_l, A2_l,
                                        dsk_l, PART, SS, outw_l,
                                        lnw + (size_t)lnx * 256,
                                        lnb + (size_t)lnx * 256, X, H);
  }

  f2b_k<<<8192, 256, 0, stream>>>(X, XB);
  gemm_bt<1><<<dim3(8, 64), 256, 0, stream>>>(XB, WW1, HH, b1, 8192, 1024, 256);
  gemm_bt<2><<<dim3(32, 64), 256, 0, stream>>>(HH, WW2, (float*)d_out, b2, 8192, 4096, 1024);
}